// Round 5
// baseline (941.019 us; speedup 1.0000x reference)
//
#include <hip/hip_runtime.h>
#include <math.h>

#define CDIM 256
#define KDIM 1024
#define TOPK 8
#define MROWS 64
#define NELEM 16777216
#define L2E 1.4426950408889634f

typedef unsigned short u16;
typedef unsigned int u32;
typedef __attribute__((ext_vector_type(8))) short s16x8;
typedef __attribute__((ext_vector_type(8))) __bf16 b16x8;
typedef __attribute__((ext_vector_type(16))) float f32x16;

#define ZERO16 {0.f,0.f,0.f,0.f,0.f,0.f,0.f,0.f,0.f,0.f,0.f,0.f,0.f,0.f,0.f,0.f}

// ws layout (bytes)
#define WS_COUNTS 64
#define WS_DN     4608
#define WS_B2     8704
#define WS_WH     16384
#define WS_DH     (WS_WH + 524288)
#define WS_DL     (WS_DH + 524288)

// smem layout (bytes)
#define SM_XH   0        // 32KB x hi
#define SM_XL   32768    // 32KB x lo
#define SM_B2   65536    // 4KB  log2e*b   (main loop)   | overlay: pd
#define SM_DN   69632    // 4KB  dict norms (main loop)  | overlay: pi
#define SM_PD   65536
#define SM_PI   69632
#define SM_PM   73728
#define SM_PS   74240
#define SM_SELP 74752
#define SM_SELI 76800
#define SM_SELM 78848
#define SM_SELS 79104
#define SM_TOT  79360

__device__ __forceinline__ u16 f2bf(float f) {
    u32 u = __builtin_bit_cast(u32, f);
    u += 0x7FFFu + ((u >> 16) & 1u);
    return (u16)(u >> 16);
}
__device__ __forceinline__ float bf2f(u16 h) {
    return __builtin_bit_cast(float, ((u32)h) << 16);
}
__device__ __forceinline__ float hi2f(u32 u) {
    return __builtin_bit_cast(float, u & 0xFFFF0000u);
}
__device__ __forceinline__ f32x16 mfma16(s16x8 a, s16x8 b, f32x16 c) {
    return __builtin_amdgcn_mfma_f32_32x32x16_bf16(
        __builtin_bit_cast(b16x8, a), __builtin_bit_cast(b16x8, b), c, 0, 0, 0);
}

// branchless sorted-ascending insert of (key, idx); 5 VALU ops per position
#define INS2(DV, CI) { float cd_ = (DV); int ci_ = (CI); \
    _Pragma("unroll") \
    for (int p_ = 0; p_ < 8; ++p_) { \
        bool lt_ = cd_ < hd[p_]; \
        float nk_ = lt_ ? cd_ : hd[p_]; \
        float ok_ = lt_ ? hd[p_] : cd_; \
        int ni_ = lt_ ? ci_ : hix[p_]; \
        int oi_ = lt_ ? hix[p_] : ci_; \
        hd[p_] = nk_; cd_ = ok_; hix[p_] = ni_; ci_ = oi_; } }

#define CE(A, B) { \
    bool sw_ = (hd[B] < hd[A]) || (hd[B] == hd[A] && hix[B] < hix[A]); \
    if (sw_) { float td_ = hd[A]; hd[A] = hd[B]; hd[B] = td_; \
               int ti_ = hix[A]; hix[A] = hix[B]; hix[B] = ti_; } }

// merge sorted 8-list in od/oi into hd/hix (both sorted ascending)
#define MERGE8() { \
    _Pragma("unroll") \
    for (int j_ = 0; j_ < 8; ++j_) { \
        float bd_ = od[7 - j_]; int bi_ = oi[7 - j_]; \
        if (bd_ < hd[j_] || (bd_ == hd[j_] && bi_ < hix[j_])) { \
            hd[j_] = bd_; hix[j_] = bi_; } } \
    CE(0,4) CE(1,5) CE(2,6) CE(3,7) \
    CE(0,2) CE(1,3) CE(4,6) CE(5,7) \
    CE(0,1) CE(2,3) CE(4,5) CE(6,7) }

// ---------------- prepass: bf16 splits (log2e folded into W, -2 into D) ----
__global__ __launch_bounds__(256)
void dl_prep(const float* __restrict__ Wm, const float* __restrict__ dict,
             const float* __restrict__ bv,
             u16* __restrict__ Wh, u16* __restrict__ Dh, u16* __restrict__ Dl,
             float* __restrict__ dn, float* __restrict__ b2)
{
    __shared__ float red[4];
    const int k = blockIdx.x, c = threadIdx.x;
    const size_t idx = ((size_t)k << 8) + c;
    Wh[idx] = f2bf(Wm[idx] * L2E);
    float d = dict[idx];
    float v = -2.0f * d;
    u16 vh = f2bf(v);
    Dh[idx] = vh;
    Dl[idx] = f2bf(v - bf2f(vh));
    float sq = d * d;
    #pragma unroll
    for (int off = 32; off; off >>= 1) sq += __shfl_down(sq, off);
    if ((c & 63) == 0) red[c >> 6] = sq;
    __syncthreads();
    if (c == 0) { dn[k] = red[0] + red[1] + red[2] + red[3]; b2[k] = bv[k] * L2E; }
}

// ---------------- main fused kernel -----------------------------------------
__global__ __launch_bounds__(512, 4)
void dl_main(const float* __restrict__ x, const float* __restrict__ dict,
             const float* __restrict__ Wm, const float* __restrict__ bv,
             const u16* __restrict__ Wh, const u16* __restrict__ Dh,
             const u16* __restrict__ Dl, const float* __restrict__ dnp,
             const float* __restrict__ b2g, float* __restrict__ out,
             float* __restrict__ loss_acc, float* __restrict__ reg_acc,
             int* __restrict__ counts)
{
    __shared__ __align__(16) char smem[SM_TOT];
    u16*   xh   = (u16*)(smem + SM_XH);
    u16*   xl   = (u16*)(smem + SM_XL);
    float* b2_s = (float*)(smem + SM_B2);
    float* dn_s = (float*)(smem + SM_DN);
    float* pd   = (float*)(smem + SM_PD);
    int*   pi   = (int*)(smem + SM_PI);
    float* pm   = (float*)(smem + SM_PM);
    float* ps   = (float*)(smem + SM_PS);
    float* selp = (float*)(smem + SM_SELP);
    int*   seli = (int*)(smem + SM_SELI);
    float* selm = (float*)(smem + SM_SELM);
    float* sels = (float*)(smem + SM_SELS);

    const int t = threadIdx.x;
    const int lane = t & 63;
    const int wid = t >> 6;
    const int n0 = blockIdx.x * MROWS;

    // ---- phase 0: stage x -> bf16 hi/lo (swizzled); b2/dn -> LDS
    {
        const int r = t & 63, cs = t >> 6;
        const float* xb = x + ((size_t)(n0 >> 12) << 20) + (n0 & 4095) + r;
        #pragma unroll 4
        for (int i = 0; i < 32; i += 2) {
            int c = cs * 32 + i;
            float g0 = xb[(size_t)c << 12];
            float g1 = xb[(size_t)(c + 1) << 12];
            u16 h0 = f2bf(g0), h1 = f2bf(g1);
            u16 e0 = f2bf(g0 - bf2f(h0)), e1 = f2bf(g1 - bf2f(h1));
            int byte = (r * 512 + c * 2) ^ ((r & 7) << 4);
            *(u32*)((char*)xh + byte) = (u32)h0 | ((u32)h1 << 16);
            *(u32*)((char*)xl + byte) = (u32)e0 | ((u32)e1 << 16);
        }
        b2_s[t] = b2g[t];  b2_s[512 + t] = b2g[512 + t];
        dn_s[t] = dnp[t];  dn_s[512 + t] = dnp[512 + t];
    }
    __syncthreads();

    const int arow = lane & 31, hl = lane >> 5;
    const int rgrp = wid & 1, agrp = wid >> 1;
    const int xrow = rgrp * 32 + arow;
    const int swz = (arow & 7) << 4;

    float m_run = -INFINITY, s_run = 0.f;
    float hd[TOPK];
    int hix[TOPK];
    #pragma unroll
    for (int j = 0; j < TOPK; ++j) { hd[j] = INFINITY; hix[j] = 0; }

    // ---- barrier-free, store-free main loop: 8 chunks of 128 atoms
    #pragma unroll 1
    for (int ck = 0; ck < 8; ++ck) {
        const size_t arow_g = (size_t)(ck * 128 + agrp * 32 + arow);
        const u16* Wp  = Wh + (arow_g << 8) + hl * 8;
        const u16* Dhp = Dh + (arow_g << 8) + hl * 8;
        const u16* Dlp = Dl + (arow_g << 8) + hl * 8;

        f32x16 accL = ZERO16, accDa = ZERO16, accDb = ZERO16;
        #pragma unroll
        for (int kst = 0; kst < 16; ++kst) {
            int boff = (xrow * 512 + hl * 16 + kst * 32) ^ swz;
            s16x8 aw  = *(const s16x8*)(Wp  + kst * 16);
            s16x8 adh = *(const s16x8*)(Dhp + kst * 16);
            s16x8 adl = *(const s16x8*)(Dlp + kst * 16);
            s16x8 bh = *(const s16x8*)((const char*)xh + boff);
            s16x8 bl = *(const s16x8*)((const char*)xl + boff);
            accL  = mfma16(aw,  bh, accL);   // log2-domain logits (hi only)
            accDa = mfma16(adh, bh, accDa);  // -2 x_hi.d_hi
            accDb = mfma16(adh, bl, accDb);  // -2 x_lo.d_hi
            accDb = mfma16(adl, bh, accDb);  // -2 x_hi.d_lo
        }

        // consume: lane-local online softmax + top-8 (16 atoms per lane)
        #pragma unroll
        for (int rg = 0; rg < 4; ++rg) {
            const int mb = ck * 128 + agrp * 32 + 8 * rg + 4 * hl;
            float4 b4 = *(const float4*)(b2_s + mb);   // LDS broadcast
            float4 n4 = *(const float4*)(dn_s + mb);   // LDS broadcast
            float lv0 = accL[4*rg+0] + b4.x, lv1 = accL[4*rg+1] + b4.y;
            float lv2 = accL[4*rg+2] + b4.z, lv3 = accL[4*rg+3] + b4.w;
            float mx = fmaxf(fmaxf(fmaxf(lv0, lv1), fmaxf(lv2, lv3)), m_run);
            s_run = s_run * exp2f(m_run - mx)
                  + exp2f(lv0 - mx) + exp2f(lv1 - mx)
                  + exp2f(lv2 - mx) + exp2f(lv3 - mx);
            m_run = mx;
            // selection key: dn - 2 x.d  (row-constant ||x||^2 dropped)
            float dv0 = n4.x + accDa[4*rg+0] + accDb[4*rg+0];
            float dv1 = n4.y + accDa[4*rg+1] + accDb[4*rg+1];
            float dv2 = n4.z + accDa[4*rg+2] + accDb[4*rg+2];
            float dv3 = n4.w + accDa[4*rg+3] + accDb[4*rg+3];
            INS2(dv0, mb + 0)
            INS2(dv1, mb + 1)
            INS2(dv2, mb + 2)
            INS2(dv3, mb + 3)
        }
    }

    // ---- rep zero-fill: issued now so stores retire during the merge tree
    float* rep0 = out + 2 + (size_t)NELEM;
    {
        float2* zb = (float2*)(rep0 + ((size_t)n0 << 10));
        #pragma unroll 8
        for (int i = 0; i < 64; ++i) zb[i * 512 + t] = make_float2(0.f, 0.f);
    }

    // ---- merge the two atom-halves (lane n <-> lane n+32): same x-row
    {
        float mo = __shfl_xor(m_run, 32);
        float so = __shfl_xor(s_run, 32);
        float mn = fmaxf(m_run, mo);
        s_run = s_run * exp2f(m_run - mn) + so * exp2f(mo - mn);
        m_run = mn;
        float od[TOPK]; int oi[TOPK];
        #pragma unroll
        for (int j = 0; j < TOPK; ++j) {
            od[j] = __shfl_xor(hd[j], 32);
            oi[j] = __shfl_xor(hix[j], 32);
        }
        MERGE8()
    }

    // ---- cross-wave merge (4 atom-groups -> 1); pd/pi overlay dead b2/dn
    __syncthreads();
    if (wid >= 4 && lane < 32) {            // agrp 2,3 publish
        int base = ((agrp - 2) * 64 + xrow);
        #pragma unroll
        for (int j = 0; j < TOPK; ++j) {
            pd[base * 8 + j] = hd[j]; pi[base * 8 + j] = hix[j];
        }
        pm[base] = m_run; ps[base] = s_run;
    }
    __syncthreads();
    if (wid < 4 && lane < 32) {             // agrp 0,1 absorb agrp 2,3
        int base = (agrp * 64 + xrow);
        float od[TOPK]; int oi[TOPK];
        #pragma unroll
        for (int j = 0; j < TOPK; ++j) {
            od[j] = pd[base * 8 + j]; oi[j] = pi[base * 8 + j];
        }
        float mo = pm[base], so = ps[base];
        float mn = fmaxf(m_run, mo);
        s_run = s_run * exp2f(m_run - mn) + so * exp2f(mo - mn);
        m_run = mn;
        MERGE8()
    }
    __syncthreads();
    if ((wid == 2 || wid == 3) && lane < 32) {   // agrp1 publish
        #pragma unroll
        for (int j = 0; j < TOPK; ++j) {
            pd[xrow * 8 + j] = hd[j]; pi[xrow * 8 + j] = hix[j];
        }
        pm[xrow] = m_run; ps[xrow] = s_run;
    }
    __syncthreads();
    if (wid < 2 && lane < 32) {                  // agrp0 final merge
        float od[TOPK]; int oi[TOPK];
        #pragma unroll
        for (int j = 0; j < TOPK; ++j) {
            od[j] = pd[xrow * 8 + j]; oi[j] = pi[xrow * 8 + j];
        }
        float mo = pm[xrow], so = ps[xrow];
        float mn = fmaxf(m_run, mo);
        s_run = s_run * exp2f(m_run - mn) + so * exp2f(mo - mn);
        m_run = mn;
        MERGE8()
        selm[xrow] = m_run;
        sels[xrow] = 1.0f / s_run;
        #pragma unroll
        for (int j = 0; j < TOPK; ++j) {
            seli[xrow * 8 + j] = hix[j];
            atomicAdd(&counts[hix[j]], 1);
        }
    }
    __syncthreads();

    // ---- recompute winner logits exactly (fp32 W, b) -> probabilities
    {
        const int row = t >> 3, j = t & 7;
        const int idxw = seli[row * 8 + j];
        const float4* wp = (const float4*)(Wm + ((size_t)idxw << 8));
        const int swr = (row & 7) << 4;
        float4 a = make_float4(0.f, 0.f, 0.f, 0.f);
        #pragma unroll 8
        for (int i = 0; i < 32; ++i) {
            int byte = (row * 512 + i * 16) ^ swr;
            uint4 H = *(const uint4*)((const char*)xh + byte);
            uint4 L = *(const uint4*)((const char*)xl + byte);
            float4 w0 = wp[i * 2], w1 = wp[i * 2 + 1];
            a.x += (bf2f((u16)H.x) + bf2f((u16)L.x)) * w0.x;
            a.y += (hi2f(H.x) + hi2f(L.x)) * w0.y;
            a.z += (bf2f((u16)H.y) + bf2f((u16)L.y)) * w0.z;
            a.w += (hi2f(H.y) + hi2f(L.y)) * w0.w;
            a.x += (bf2f((u16)H.z) + bf2f((u16)L.z)) * w1.x;
            a.y += (hi2f(H.z) + hi2f(L.z)) * w1.y;
            a.z += (bf2f((u16)H.w) + bf2f((u16)L.w)) * w1.z;
            a.w += (hi2f(H.w) + hi2f(L.w)) * w1.w;
        }
        float lg = (a.x + a.y) + (a.z + a.w) + bv[idxw];
        float p = exp2f(lg * L2E - selm[row]) * sels[row];
        selp[row * 8 + j] = p;
        float v2 = p;
        #pragma unroll
        for (int off = 32; off; off >>= 1) v2 += __shfl_down(v2, off);
        if (lane == 0) atomicAdd(reg_acc, v2);
    }
    __syncthreads();

    // ---- rep scatter (zeros retired to L2 before the barrier's vmcnt drain)
    {
        int rr = t >> 3, j = t & 7;
        rep0[((size_t)(n0 + rr) << 10) + seli[rr * 8 + j]] = selp[rr * 8 + j];
    }

    // ---- recon (flat .view semantics) + fused MSE (x rebuilt from LDS hi+lo)
    float lsum = 0.f;
    {
        int rr = t >> 3, tl = t & 7;
        size_t n = (size_t)(n0 + rr);
        const int swr = (rr & 7) << 4;
        float acc[32];
        #pragma unroll
        for (int i = 0; i < 32; ++i) acc[i] = 0.f;
        #pragma unroll
        for (int j = 0; j < TOPK; ++j) {
            float p = selp[rr * 8 + j];
            const float* dp = dict + ((size_t)seli[rr * 8 + j] << 8) + tl * 32;
            #pragma unroll
            for (int i = 0; i < 32; i += 4) {
                float4 d4 = *(const float4*)(dp + i);
                acc[i]     += p * d4.x; acc[i + 1] += p * d4.y;
                acc[i + 2] += p * d4.z; acc[i + 3] += p * d4.w;
            }
        }
        float* ro = out + 1 + (n << 8) + tl * 32;
        #pragma unroll
        for (int i = 0; i < 4; ++i) {
            int byte = (rr * 512 + tl * 64 + i * 16) ^ swr;
            uint4 H = *(const uint4*)((const char*)xh + byte);
            uint4 L = *(const uint4*)((const char*)xl + byte);
            float xv[8];
            xv[0] = bf2f((u16)H.x) + bf2f((u16)L.x);
            xv[1] = hi2f(H.x) + hi2f(L.x);
            xv[2] = bf2f((u16)H.y) + bf2f((u16)L.y);
            xv[3] = hi2f(H.y) + hi2f(L.y);
            xv[4] = bf2f((u16)H.z) + bf2f((u16)L.z);
            xv[5] = hi2f(H.z) + hi2f(L.z);
            xv[6] = bf2f((u16)H.w) + bf2f((u16)L.w);
            xv[7] = hi2f(H.w) + hi2f(L.w);
            #pragma unroll
            for (int q = 0; q < 8; ++q) {
                float av = acc[i * 8 + q];
                float e = xv[q] - av;
                lsum += e * e;
                ro[i * 8 + q] = av;
            }
        }
    }
    {
        #pragma unroll
        for (int off = 32; off; off >>= 1) lsum += __shfl_down(lsum, off);
        if (lane == 0) atomicAdd(loss_acc, lsum);
    }
}

// ---------------- finalize scalars -------------------------------------------
__global__ void dl_final(const float* __restrict__ loss_acc,
                         const float* __restrict__ reg_acc,
                         const int* __restrict__ counts,
                         float* __restrict__ out)
{
    __shared__ float red[4];
    int t = threadIdx.x;
    float e = 0.f;
    for (int k = t; k < KDIM; k += 256) {
        float p = (float)counts[k] * (1.0f / 524288.0f);
        e += p * logf(p + 1e-10f);
    }
    #pragma unroll
    for (int off = 32; off; off >>= 1) e += __shfl_down(e, off);
    if ((t & 63) == 0) red[t >> 6] = e;
    __syncthreads();
    if (t == 0) {
        float et = red[0] + red[1] + red[2] + red[3];
        out[(size_t)NELEM + 1] = __expf(-et);                     // perplexity
        out[0] = 2.0f * loss_acc[0] / (float)NELEM + reg_acc[0];  // loss + reg
    }
}

extern "C" void kernel_launch(void* const* d_in, const int* in_sizes, int n_in,
                              void* d_out, int out_size, void* d_ws, size_t ws_size,
                              hipStream_t stream) {
    const float* x    = (const float*)d_in[0];
    const float* dict = (const float*)d_in[1];
    const float* Wm   = (const float*)d_in[2];
    const float* bv   = (const float*)d_in[3];
    float* out = (float*)d_out;

    float* loss_acc = (float*)d_ws;
    float* reg_acc  = loss_acc + 1;
    int*   counts   = (int*)((char*)d_ws + WS_COUNTS);
    float* dn       = (float*)((char*)d_ws + WS_DN);
    float* b2       = (float*)((char*)d_ws + WS_B2);
    u16*   Wh       = (u16*)((char*)d_ws + WS_WH);
    u16*   Dh       = (u16*)((char*)d_ws + WS_DH);
    u16*   Dl       = (u16*)((char*)d_ws + WS_DL);

    hipMemsetAsync(d_ws, 0, 4608, stream);
    dl_prep<<<KDIM, 256, 0, stream>>>(Wm, dict, bv, Wh, Dh, Dl, dn, b2);
    dl_main<<<65536 / MROWS, 512, 0, stream>>>(x, dict, Wm, bv, Wh, Dh, Dl, dn,
                                               b2, out, loss_acc, reg_acc, counts);
    dl_final<<<1, 256, 0, stream>>>(loss_acc, reg_acc, counts, out);
}

// Round 6
// 650.478 us; speedup vs baseline: 1.4467x; 1.4467x over previous
//
#include <hip/hip_runtime.h>
#include <math.h>

#define CDIM 256
#define KDIM 1024
#define TOPK 8
#define MROWS 64
#define NELEM 16777216
#define L2E 1.4426950408889634f

typedef unsigned short u16;
typedef unsigned int u32;
typedef __attribute__((ext_vector_type(8))) short s16x8;
typedef __attribute__((ext_vector_type(8))) __bf16 b16x8;
typedef __attribute__((ext_vector_type(16))) float f32x16;

#define ZERO16 {0.f,0.f,0.f,0.f,0.f,0.f,0.f,0.f,0.f,0.f,0.f,0.f,0.f,0.f,0.f,0.f}

// ws layout (bytes)
#define WS_COUNTS 64
#define WS_DN     4608
#define WS_B2     8704
#define WS_WH     16384
#define WS_DH     (WS_WH + 524288)
#define WS_DL     (WS_DH + 524288)

// smem layout (bytes); merge/sel overlays sit in the dead x-tile [0,65536)
#define SM_XH   0
#define SM_XL   32768
#define SM_B2   65536
#define SM_DN   69632
#define SM_TOT  73728
#define SM_PD   0        // 16KB  pd[row][wave][8]
#define SM_PI   16384    // 16KB
#define SM_PM   32768    // 2KB   pm[row][wave]
#define SM_PS   34816    // 2KB
#define SM_SELI 36864    // 2KB
#define SM_SELM 38912    // 256B
#define SM_SELS 39168    // 256B
#define SM_SELP 39424    // 2KB

__device__ __forceinline__ u16 f2bf(float f) {
    u32 u = __builtin_bit_cast(u32, f);
    u += 0x7FFFu + ((u >> 16) & 1u);
    return (u16)(u >> 16);
}
__device__ __forceinline__ float bf2f(u16 h) {
    return __builtin_bit_cast(float, ((u32)h) << 16);
}
__device__ __forceinline__ f32x16 mfma16(s16x8 a, s16x8 b, f32x16 c) {
    return __builtin_amdgcn_mfma_f32_32x32x16_bf16(
        __builtin_bit_cast(b16x8, a), __builtin_bit_cast(b16x8, b), c, 0, 0, 0);
}

// branchless sorted-ascending insert of (key, idx)
#define INS2(HD, HX, DV, CI) { float cd_ = (DV); int ci_ = (CI); \
    _Pragma("unroll") \
    for (int p_ = 0; p_ < 8; ++p_) { \
        bool lt_ = cd_ < HD[p_]; \
        float nk_ = lt_ ? cd_ : HD[p_]; \
        float ok_ = lt_ ? HD[p_] : cd_; \
        int ni_ = lt_ ? ci_ : HX[p_]; \
        int oi_ = lt_ ? HX[p_] : ci_; \
        HD[p_] = nk_; cd_ = ok_; HX[p_] = ni_; ci_ = oi_; } }

#define CE(HD, HX, A, B) { \
    bool sw_ = (HD[B] < HD[A]) || (HD[B] == HD[A] && HX[B] < HX[A]); \
    if (sw_) { float td_ = HD[A]; HD[A] = HD[B]; HD[B] = td_; \
               int ti_ = HX[A]; HX[A] = HX[B]; HX[B] = ti_; } }

// merge sorted 8-list od/oi into HD/HX (both sorted ascending)
#define MERGE8(HD, HX, OD, OI) { \
    _Pragma("unroll") \
    for (int j_ = 0; j_ < 8; ++j_) { \
        float bd_ = OD[7 - j_]; int bi_ = OI[7 - j_]; \
        if (bd_ < HD[j_] || (bd_ == HD[j_] && bi_ < HX[j_])) { \
            HD[j_] = bd_; HX[j_] = bi_; } } \
    CE(HD,HX,0,4) CE(HD,HX,1,5) CE(HD,HX,2,6) CE(HD,HX,3,7) \
    CE(HD,HX,0,2) CE(HD,HX,1,3) CE(HD,HX,4,6) CE(HD,HX,5,7) \
    CE(HD,HX,0,1) CE(HD,HX,2,3) CE(HD,HX,4,5) CE(HD,HX,6,7) }

// ---------------- prepass: bf16 splits (log2e folded into W/b, -2 into D) ---
__global__ __launch_bounds__(256)
void dl_prep(const float* __restrict__ Wm, const float* __restrict__ dict,
             const float* __restrict__ bv,
             u16* __restrict__ Wh, u16* __restrict__ Dh, u16* __restrict__ Dl,
             float* __restrict__ dn, float* __restrict__ b2)
{
    __shared__ float red[4];
    const int k = blockIdx.x, c = threadIdx.x;
    const size_t idx = ((size_t)k << 8) + c;
    Wh[idx] = f2bf(Wm[idx] * L2E);
    float d = dict[idx];
    float v = -2.0f * d;
    u16 vh = f2bf(v);
    Dh[idx] = vh;
    Dl[idx] = f2bf(v - bf2f(vh));
    float sq = d * d;
    #pragma unroll
    for (int off = 32; off; off >>= 1) sq += __shfl_down(sq, off);
    if ((c & 63) == 0) red[c >> 6] = sq;
    __syncthreads();
    if (c == 0) { dn[k] = red[0] + red[1] + red[2] + red[3]; b2[k] = bv[k] * L2E; }
}

// ---------------- main fused kernel -----------------------------------------
__global__ __launch_bounds__(512, 4)
void dl_main(const float* __restrict__ x, const float* __restrict__ dict,
             const float* __restrict__ Wm, const float* __restrict__ bv,
             const u16* __restrict__ Wh, const u16* __restrict__ Dh,
             const u16* __restrict__ Dl, const float* __restrict__ dnp,
             const float* __restrict__ b2g, float* __restrict__ out,
             float* __restrict__ loss_acc, float* __restrict__ reg_acc,
             int* __restrict__ counts)
{
    __shared__ __align__(16) char smem[SM_TOT];
    u16*   xh   = (u16*)(smem + SM_XH);
    u16*   xl   = (u16*)(smem + SM_XL);
    float* b2_s = (float*)(smem + SM_B2);
    float* dn_s = (float*)(smem + SM_DN);
    float* pd   = (float*)(smem + SM_PD);
    int*   pi   = (int*)(smem + SM_PI);
    float* pm   = (float*)(smem + SM_PM);
    float* ps   = (float*)(smem + SM_PS);
    int*   seli = (int*)(smem + SM_SELI);
    float* selm = (float*)(smem + SM_SELM);
    float* sels = (float*)(smem + SM_SELS);
    float* selp = (float*)(smem + SM_SELP);

    const int t = threadIdx.x;
    const int lane = t & 63;
    const int wid = t >> 6;
    const int n0 = blockIdx.x * MROWS;

    // ---- phase 0: stage x -> bf16 hi/lo (swizzled); b2/dn -> LDS
    {
        const int r = t & 63, cs = t >> 6;
        const float* xb = x + ((size_t)(n0 >> 12) << 20) + (n0 & 4095) + r;
        #pragma unroll 4
        for (int i = 0; i < 32; i += 2) {
            int c = cs * 32 + i;
            float g0 = xb[(size_t)c << 12];
            float g1 = xb[(size_t)(c + 1) << 12];
            u16 h0 = f2bf(g0), h1 = f2bf(g1);
            u16 e0 = f2bf(g0 - bf2f(h0)), e1 = f2bf(g1 - bf2f(h1));
            int byte = (r * 512 + c * 2) ^ ((r & 7) << 4);
            *(u32*)((char*)xh + byte) = (u32)h0 | ((u32)h1 << 16);
            *(u32*)((char*)xl + byte) = (u32)e0 | ((u32)e1 << 16);
        }
        b2_s[t] = b2g[t];  b2_s[512 + t] = b2g[512 + t];
        dn_s[t] = dnp[t];  dn_s[512 + t] = dnp[512 + t];
    }
    __syncthreads();

    // ---- rep zero-fill early (overlaps with compute; R3-proven position)
    float* rep0 = out + 2 + (size_t)NELEM;
    {
        float2* zb = (float2*)(rep0 + ((size_t)n0 << 10));
        #pragma unroll 8
        for (int i = 0; i < 64; ++i) zb[i * 512 + t] = make_float2(0.f, 0.f);
    }

    const int arow = lane & 31, hl = lane >> 5;
    const int swz = (arow & 7) << 4;

    float m0 = -INFINITY, s0 = 0.f, m1 = -INFINITY, s1 = 0.f;
    float hd0[TOPK], hd1[TOPK];
    int hix0[TOPK], hix1[TOPK];
    #pragma unroll
    for (int j = 0; j < TOPK; ++j) {
        hd0[j] = INFINITY; hix0[j] = 0; hd1[j] = INFINITY; hix1[j] = 0;
    }

    // ---- barrier-free main loop: 4 chunks of 256 atoms; wave owns one
    //      32-atom tile per chunk and computes BOTH x-row tiles (atom
    //      fragments fetched once per block)
    #pragma unroll 1
    for (int ck = 0; ck < 4; ++ck) {
        const size_t abase = (size_t)(ck * 256 + wid * 32 + arow);
        // ---- L phase: logits for both row tiles
        const u16* Wp = Wh + (abase << 8) + hl * 8;
        f32x16 accL0 = ZERO16, accL1 = ZERO16;
        #pragma unroll 2
        for (int kst = 0; kst < 16; ++kst) {
            int bo = (arow * 512 + hl * 16 + kst * 32) ^ swz;
            s16x8 aw  = *(const s16x8*)(Wp + kst * 16);
            s16x8 bh0 = *(const s16x8*)((const char*)xh + bo);
            s16x8 bh1 = *(const s16x8*)((const char*)xh + bo + 32 * 512);
            accL0 = mfma16(aw, bh0, accL0);
            accL1 = mfma16(aw, bh1, accL1);
        }
        // L consume: online softmax for row arow (tile0) and arow+32 (tile1)
        #pragma unroll
        for (int rg = 0; rg < 4; ++rg) {
            const int mb = ck * 256 + wid * 32 + 8 * rg + 4 * hl;
            float4 b4 = *(const float4*)(b2_s + mb);
            float a0 = accL0[4*rg+0] + b4.x, a1 = accL0[4*rg+1] + b4.y;
            float a2 = accL0[4*rg+2] + b4.z, a3 = accL0[4*rg+3] + b4.w;
            float mx = fmaxf(fmaxf(fmaxf(a0, a1), fmaxf(a2, a3)), m0);
            s0 = s0 * exp2f(m0 - mx)
               + ((exp2f(a0 - mx) + exp2f(a1 - mx))
                + (exp2f(a2 - mx) + exp2f(a3 - mx)));
            m0 = mx;
            float c0 = accL1[4*rg+0] + b4.x, c1 = accL1[4*rg+1] + b4.y;
            float c2 = accL1[4*rg+2] + b4.z, c3 = accL1[4*rg+3] + b4.w;
            float my = fmaxf(fmaxf(fmaxf(c0, c1), fmaxf(c2, c3)), m1);
            s1 = s1 * exp2f(m1 - my)
               + ((exp2f(c0 - my) + exp2f(c1 - my))
                + (exp2f(c2 - my) + exp2f(c3 - my)));
            m1 = my;
        }
        // ---- D phase: -2 x.d (3-product bf16 split) for both row tiles
        const u16* Dhp = Dh + (abase << 8) + hl * 8;
        const u16* Dlp = Dl + (abase << 8) + hl * 8;
        f32x16 accD0 = ZERO16, accD1 = ZERO16;
        #pragma unroll 2
        for (int kst = 0; kst < 16; ++kst) {
            int bo = (arow * 512 + hl * 16 + kst * 32) ^ swz;
            s16x8 adh = *(const s16x8*)(Dhp + kst * 16);
            s16x8 adl = *(const s16x8*)(Dlp + kst * 16);
            s16x8 bh0 = *(const s16x8*)((const char*)xh + bo);
            s16x8 bl0 = *(const s16x8*)((const char*)xl + bo);
            s16x8 bh1 = *(const s16x8*)((const char*)xh + bo + 32 * 512);
            s16x8 bl1 = *(const s16x8*)((const char*)xl + bo + 32 * 512);
            accD0 = mfma16(adh, bh0, accD0);
            accD0 = mfma16(adh, bl0, accD0);
            accD0 = mfma16(adl, bh0, accD0);
            accD1 = mfma16(adh, bh1, accD1);
            accD1 = mfma16(adh, bl1, accD1);
            accD1 = mfma16(adl, bh1, accD1);
        }
        // D consume: top-8 smallest (dn - 2 x.d) per row
        #pragma unroll
        for (int rg = 0; rg < 4; ++rg) {
            const int mb = ck * 256 + wid * 32 + 8 * rg + 4 * hl;
            float4 n4 = *(const float4*)(dn_s + mb);
            float d0 = n4.x + accD0[4*rg+0];
            float d1 = n4.y + accD0[4*rg+1];
            float d2 = n4.z + accD0[4*rg+2];
            float d3 = n4.w + accD0[4*rg+3];
            INS2(hd0, hix0, d0, mb + 0)
            INS2(hd0, hix0, d1, mb + 1)
            INS2(hd0, hix0, d2, mb + 2)
            INS2(hd0, hix0, d3, mb + 3)
            float e0 = n4.x + accD1[4*rg+0];
            float e1 = n4.y + accD1[4*rg+1];
            float e2 = n4.z + accD1[4*rg+2];
            float e3 = n4.w + accD1[4*rg+3];
            INS2(hd1, hix1, e0, mb + 0)
            INS2(hd1, hix1, e1, mb + 1)
            INS2(hd1, hix1, e2, mb + 2)
            INS2(hd1, hix1, e3, mb + 3)
        }
    }

    // ---- intra-wave merge (lane n <-> n+32 hold same rows, other atoms)
    {
        float mo = __shfl_xor(m0, 32), so = __shfl_xor(s0, 32);
        float mn = fmaxf(m0, mo);
        s0 = s0 * exp2f(m0 - mn) + so * exp2f(mo - mn);
        m0 = mn;
        mo = __shfl_xor(m1, 32); so = __shfl_xor(s1, 32);
        mn = fmaxf(m1, mo);
        s1 = s1 * exp2f(m1 - mn) + so * exp2f(mo - mn);
        m1 = mn;
        float od[TOPK]; int oi[TOPK];
        #pragma unroll
        for (int j = 0; j < TOPK; ++j) {
            od[j] = __shfl_xor(hd0[j], 32); oi[j] = __shfl_xor(hix0[j], 32);
        }
        MERGE8(hd0, hix0, od, oi)
        #pragma unroll
        for (int j = 0; j < TOPK; ++j) {
            od[j] = __shfl_xor(hd1[j], 32); oi[j] = __shfl_xor(hix1[j], 32);
        }
        MERGE8(hd1, hix1, od, oi)
    }

    // ---- publish all 8 wave-lists per row into the dead x-tile LDS
    __syncthreads();   // all main-loop LDS reads complete
    {
        const int row = (lane < 32) ? arow : (arow + 32);
        const int base = row * 64 + wid * 8;
        if (lane < 32) {
            #pragma unroll
            for (int j = 0; j < TOPK; ++j) { pd[base + j] = hd0[j]; pi[base + j] = hix0[j]; }
            pm[row * 8 + wid] = m0; ps[row * 8 + wid] = s0;
        } else {
            #pragma unroll
            for (int j = 0; j < TOPK; ++j) { pd[base + j] = hd1[j]; pi[base + j] = hix1[j]; }
            pm[row * 8 + wid] = m1; ps[row * 8 + wid] = s1;
        }
    }
    __syncthreads();

    // ---- final merge: one 8-thread group per row, 3-round bitonic
    {
        const int row = t >> 3, src = t & 7;
        float hd[TOPK]; int hix[TOPK];
        #pragma unroll
        for (int j = 0; j < TOPK; ++j) {
            hd[j] = pd[row * 64 + src * 8 + j];
            hix[j] = pi[row * 64 + src * 8 + j];
        }
        float m = pm[row * 8 + src], s = ps[row * 8 + src];
        #pragma unroll
        for (int k = 1; k <= 4; k <<= 1) {
            float mo = __shfl_xor(m, k), so = __shfl_xor(s, k);
            float mn = fmaxf(m, mo);
            s = s * exp2f(m - mn) + so * exp2f(mo - mn);
            m = mn;
            float od[TOPK]; int oi[TOPK];
            #pragma unroll
            for (int j = 0; j < TOPK; ++j) {
                od[j] = __shfl_xor(hd[j], k); oi[j] = __shfl_xor(hix[j], k);
            }
            MERGE8(hd, hix, od, oi)
        }
        if (src == 0) {
            selm[row] = m;
            sels[row] = 1.0f / s;
            #pragma unroll
            for (int j = 0; j < TOPK; ++j) {
                seli[row * 8 + j] = hix[j];
                atomicAdd(&counts[hix[j]], 1);
            }
        }
    }
    __syncthreads();

    // ---- recompute winner logits exactly (fp32 x, W, b) -> probabilities
    {
        const int row = t >> 3, j = t & 7;
        const int idxw = seli[row * 8 + j];
        const float4* wp = (const float4*)(Wm + ((size_t)idxw << 8));
        const float4* xp = (const float4*)(x + ((size_t)(n0 + row) << 8));
        float4 a = make_float4(0.f, 0.f, 0.f, 0.f);
        #pragma unroll 8
        for (int i = 0; i < 64; ++i) {
            float4 xv = xp[i]; float4 wv = wp[i];
            a.x += xv.x * wv.x; a.y += xv.y * wv.y;
            a.z += xv.z * wv.z; a.w += xv.w * wv.w;
        }
        float lg = (a.x + a.y) + (a.z + a.w) + bv[idxw];
        float p = exp2f(lg * L2E - selm[row]) * sels[row];
        selp[row * 8 + j] = p;
        float v2 = p;
        #pragma unroll
        for (int off = 32; off; off >>= 1) v2 += __shfl_down(v2, off);
        if (lane == 0) atomicAdd(reg_acc, v2);
    }
    __syncthreads();

    // ---- rep scatter
    {
        int rr = t >> 3, j = t & 7;
        rep0[((size_t)(n0 + rr) << 10) + seli[rr * 8 + j]] = selp[rr * 8 + j];
    }

    // ---- recon (flat .view semantics) + fused MSE vs x (flat, coalesced)
    float lsum = 0.f;
    {
        int rr = t >> 3, tl = t & 7;
        size_t n = (size_t)(n0 + rr);
        float acc[32];
        #pragma unroll
        for (int i = 0; i < 32; ++i) acc[i] = 0.f;
        #pragma unroll
        for (int j = 0; j < TOPK; ++j) {
            float p = selp[rr * 8 + j];
            const float* dp = dict + ((size_t)seli[rr * 8 + j] << 8) + tl * 32;
            #pragma unroll
            for (int i = 0; i < 32; i += 4) {
                float4 d4 = *(const float4*)(dp + i);
                acc[i]     += p * d4.x; acc[i + 1] += p * d4.y;
                acc[i + 2] += p * d4.z; acc[i + 3] += p * d4.w;
            }
        }
        const float* xf = x + (n << 8) + tl * 32;
        float* ro = out + 1 + (n << 8) + tl * 32;
        #pragma unroll
        for (int i = 0; i < 32; i += 4) {
            float4 xv = *(const float4*)(xf + i);
            float e0 = xv.x - acc[i],     e1 = xv.y - acc[i + 1];
            float e2 = xv.z - acc[i + 2], e3 = xv.w - acc[i + 3];
            lsum += e0 * e0 + e1 * e1 + e2 * e2 + e3 * e3;
            ro[i] = acc[i]; ro[i + 1] = acc[i + 1];
            ro[i + 2] = acc[i + 2]; ro[i + 3] = acc[i + 3];
        }
    }
    {
        #pragma unroll
        for (int off = 32; off; off >>= 1) lsum += __shfl_down(lsum, off);
        if (lane == 0) atomicAdd(loss_acc, lsum);
    }
}

// ---------------- finalize scalars -------------------------------------------
__global__ void dl_final(const float* __restrict__ loss_acc,
                         const float* __restrict__ reg_acc,
                         const int* __restrict__ counts,
                         float* __restrict__ out)
{
    __shared__ float red[4];
    int t = threadIdx.x;
    float e = 0.f;
    for (int k = t; k < KDIM; k += 256) {
        float p = (float)counts[k] * (1.0f / 524288.0f);
        e += p * logf(p + 1e-10f);
    }
    #pragma unroll
    for (int off = 32; off; off >>= 1) e += __shfl_down(e, off);
    if ((t & 63) == 0) red[t >> 6] = e;
    __syncthreads();
    if (t == 0) {
        float et = red[0] + red[1] + red[2] + red[3];
        out[(size_t)NELEM + 1] = __expf(-et);                     // perplexity
        out[0] = 2.0f * loss_acc[0] / (float)NELEM + reg_acc[0];  // loss + reg
    }
}

extern "C" void kernel_launch(void* const* d_in, const int* in_sizes, int n_in,
                              void* d_out, int out_size, void* d_ws, size_t ws_size,
                              hipStream_t stream) {
    const float* x    = (const float*)d_in[0];
    const float* dict = (const float*)d_in[1];
    const float* Wm   = (const float*)d_in[2];
    const float* bv   = (const float*)d_in[3];
    float* out = (float*)d_out;

    float* loss_acc = (float*)d_ws;
    float* reg_acc  = loss_acc + 1;
    int*   counts   = (int*)((char*)d_ws + WS_COUNTS);
    float* dn       = (float*)((char*)d_ws + WS_DN);
    float* b2       = (float*)((char*)d_ws + WS_B2);
    u16*   Wh       = (u16*)((char*)d_ws + WS_WH);
    u16*   Dh       = (u16*)((char*)d_ws + WS_DH);
    u16*   Dl       = (u16*)((char*)d_ws + WS_DL);

    hipMemsetAsync(d_ws, 0, 4608, stream);
    dl_prep<<<KDIM, 256, 0, stream>>>(Wm, dict, bv, Wh, Dh, Dl, dn, b2);
    dl_main<<<65536 / MROWS, 512, 0, stream>>>(x, dict, Wm, bv, Wh, Dh, Dl, dn,
                                               b2, out, loss_acc, reg_acc, counts);
    dl_final<<<1, 256, 0, stream>>>(loss_acc, reg_acc, counts, out);
}

// Round 7
// 619.477 us; speedup vs baseline: 1.5191x; 1.0500x over previous
//
#include <hip/hip_runtime.h>
#include <math.h>

#define CDIM 256
#define KDIM 1024
#define TOPK 8
#define MROWS 64
#define NELEM 16777216
#define L2E 1.4426950408889634f

typedef unsigned short u16;
typedef unsigned int u32;
typedef __attribute__((ext_vector_type(8))) short s16x8;
typedef __attribute__((ext_vector_type(8))) __bf16 b16x8;
typedef __attribute__((ext_vector_type(16))) float f32x16;

#define ZERO16 {0.f,0.f,0.f,0.f,0.f,0.f,0.f,0.f,0.f,0.f,0.f,0.f,0.f,0.f,0.f,0.f}

// ws layout (bytes)
#define WS_COUNTS 64
#define WS_DN     4608
#define WS_B2     8704
#define WS_WH     16384
#define WS_DH     (WS_WH + 524288)
#define WS_DL     (WS_DH + 524288)

// smem layout (bytes). xh [0,32K) stays LIVE through the epilogue (logit
// recompute needs the true x_flat rows). Overlays sit on xl/b2/dn only.
#define SM_XH   0
#define SM_XL   32768
#define SM_B2   65536
#define SM_DN   69632
#define SM_PD   32768    // 16K over xl (dead after D phase)
#define SM_PI   49152    // 16K
#define SM_PM   65536    // 2K over b2
#define SM_PS   67584    // 2K
#define SM_SELI 69632    // 2K over dn
#define SM_SELP 71680    // 2K
#define SM_SELM 73728    // 256B
#define SM_SELS 73984    // 256B
#define SM_TOT  74240    // x2 = 148480 <= 163840 -> 2 blocks/CU

__device__ __forceinline__ u16 f2bf(float f) {
    u32 u = __builtin_bit_cast(u32, f);
    u += 0x7FFFu + ((u >> 16) & 1u);
    return (u16)(u >> 16);
}
__device__ __forceinline__ float bf2f(u16 h) {
    return __builtin_bit_cast(float, ((u32)h) << 16);
}
__device__ __forceinline__ float hi2f(u32 u) {
    return __builtin_bit_cast(float, u & 0xFFFF0000u);
}
__device__ __forceinline__ f32x16 mfma16(s16x8 a, s16x8 b, f32x16 c) {
    return __builtin_amdgcn_mfma_f32_32x32x16_bf16(
        __builtin_bit_cast(b16x8, a), __builtin_bit_cast(b16x8, b), c, 0, 0, 0);
}
// order-preserving float -> u32 (ascending)
__device__ __forceinline__ u32 mono(float f) {
    u32 u = __builtin_bit_cast(u32, f);
    int m = (int)u >> 31;
    return u ^ (u32)(m | (int)0x80000000);
}
__device__ __forceinline__ float unmono(u32 v) {
    int m = (int)v >> 31;
    return __builtin_bit_cast(float, v ^ (u32)((int)0x80000000 | ~m));
}

// packed sorted-ascending insert: 2 VALU per position
#define INSP(HK, PK) { u32 c_ = (PK); \
    _Pragma("unroll") \
    for (int p_ = 0; p_ < 8; ++p_) { \
        u32 lo_ = c_ < HK[p_] ? c_ : HK[p_]; \
        u32 hi_ = c_ < HK[p_] ? HK[p_] : c_; \
        HK[p_] = lo_; c_ = hi_; } }

#define CE(HD, HX, A, B) { \
    bool sw_ = (HD[B] < HD[A]) || (HD[B] == HD[A] && HX[B] < HX[A]); \
    if (sw_) { float td_ = HD[A]; HD[A] = HD[B]; HD[B] = td_; \
               int ti_ = HX[A]; HX[A] = HX[B]; HX[B] = ti_; } }

#define MERGE8(HD, HX, OD, OI) { \
    _Pragma("unroll") \
    for (int j_ = 0; j_ < 8; ++j_) { \
        float bd_ = OD[7 - j_]; int bi_ = OI[7 - j_]; \
        if (bd_ < HD[j_] || (bd_ == HD[j_] && bi_ < HX[j_])) { \
            HD[j_] = bd_; HX[j_] = bi_; } } \
    CE(HD,HX,0,4) CE(HD,HX,1,5) CE(HD,HX,2,6) CE(HD,HX,3,7) \
    CE(HD,HX,0,2) CE(HD,HX,1,3) CE(HD,HX,4,6) CE(HD,HX,5,7) \
    CE(HD,HX,0,1) CE(HD,HX,2,3) CE(HD,HX,4,5) CE(HD,HX,6,7) }

// chunk-level online softmax over 16 logits (one rescale per chunk)
#define SMAX_TILE(ACC, MM, SS) { \
    float lv_[16]; \
    _Pragma("unroll") \
    for (int rg_ = 0; rg_ < 4; ++rg_) { \
        lv_[4*rg_+0] = ACC[4*rg_+0] + bv4[rg_].x; \
        lv_[4*rg_+1] = ACC[4*rg_+1] + bv4[rg_].y; \
        lv_[4*rg_+2] = ACC[4*rg_+2] + bv4[rg_].z; \
        lv_[4*rg_+3] = ACC[4*rg_+3] + bv4[rg_].w; } \
    float x0_ = fmaxf(lv_[0],lv_[1]),  x1_ = fmaxf(lv_[2],lv_[3]); \
    float x2_ = fmaxf(lv_[4],lv_[5]),  x3_ = fmaxf(lv_[6],lv_[7]); \
    float x4_ = fmaxf(lv_[8],lv_[9]),  x5_ = fmaxf(lv_[10],lv_[11]); \
    float x6_ = fmaxf(lv_[12],lv_[13]), x7_ = fmaxf(lv_[14],lv_[15]); \
    x0_ = fmaxf(x0_,x1_); x2_ = fmaxf(x2_,x3_); \
    x4_ = fmaxf(x4_,x5_); x6_ = fmaxf(x6_,x7_); \
    float mn_ = fmaxf(fmaxf(fmaxf(x0_,x2_), fmaxf(x4_,x6_)), MM); \
    float e0_ = exp2f(lv_[0]-mn_) + exp2f(lv_[1]-mn_); \
    float e1_ = exp2f(lv_[2]-mn_) + exp2f(lv_[3]-mn_); \
    float e2_ = exp2f(lv_[4]-mn_) + exp2f(lv_[5]-mn_); \
    float e3_ = exp2f(lv_[6]-mn_) + exp2f(lv_[7]-mn_); \
    float e4_ = exp2f(lv_[8]-mn_) + exp2f(lv_[9]-mn_); \
    float e5_ = exp2f(lv_[10]-mn_) + exp2f(lv_[11]-mn_); \
    float e6_ = exp2f(lv_[12]-mn_) + exp2f(lv_[13]-mn_); \
    float e7_ = exp2f(lv_[14]-mn_) + exp2f(lv_[15]-mn_); \
    float sa_ = ((e0_+e1_) + (e2_+e3_)) + ((e4_+e5_) + (e6_+e7_)); \
    SS = SS * exp2f(MM - mn_) + sa_; MM = mn_; }

// ---------------- prepass: bf16 splits (log2e folded into W/b, -2 into D) ---
__global__ __launch_bounds__(256)
void dl_prep(const float* __restrict__ Wm, const float* __restrict__ dict,
             const float* __restrict__ bv,
             u16* __restrict__ Wh, u16* __restrict__ Dh, u16* __restrict__ Dl,
             float* __restrict__ dn, float* __restrict__ b2)
{
    __shared__ float red[4];
    const int k = blockIdx.x, c = threadIdx.x;
    const size_t idx = ((size_t)k << 8) + c;
    Wh[idx] = f2bf(Wm[idx] * L2E);
    float d = dict[idx];
    float v = -2.0f * d;
    u16 vh = f2bf(v);
    Dh[idx] = vh;
    Dl[idx] = f2bf(v - bf2f(vh));
    float sq = d * d;
    #pragma unroll
    for (int off = 32; off; off >>= 1) sq += __shfl_down(sq, off);
    if ((c & 63) == 0) red[c >> 6] = sq;
    __syncthreads();
    if (c == 0) { dn[k] = red[0] + red[1] + red[2] + red[3]; b2[k] = bv[k] * L2E; }
}

// ---------------- main fused kernel -----------------------------------------
__global__ __launch_bounds__(512, 4)
void dl_main(const float* __restrict__ x, const float* __restrict__ dict,
             const float* __restrict__ Wm, const float* __restrict__ bv,
             const u16* __restrict__ Wh, const u16* __restrict__ Dh,
             const u16* __restrict__ Dl, const float* __restrict__ dnp,
             const float* __restrict__ b2g, float* __restrict__ out,
             float* __restrict__ loss_acc, float* __restrict__ reg_acc,
             int* __restrict__ counts)
{
    __shared__ __align__(16) char smem[SM_TOT];
    u16*   xh   = (u16*)(smem + SM_XH);
    u16*   xl   = (u16*)(smem + SM_XL);
    float* b2_s = (float*)(smem + SM_B2);
    float* dn_s = (float*)(smem + SM_DN);
    float* pd   = (float*)(smem + SM_PD);
    int*   pi   = (int*)(smem + SM_PI);
    float* pm   = (float*)(smem + SM_PM);
    float* ps   = (float*)(smem + SM_PS);
    int*   seli = (int*)(smem + SM_SELI);
    float* selp = (float*)(smem + SM_SELP);
    float* selm = (float*)(smem + SM_SELM);
    float* sels = (float*)(smem + SM_SELS);

    const int t = threadIdx.x;
    const int lane = t & 63;
    const int wid = t >> 6;
    const int n0 = blockIdx.x * MROWS;

    // ---- phase 0: stage x -> bf16 hi/lo (swizzled); b2/dn -> LDS
    {
        const int r = t & 63, cs = t >> 6;
        const float* xb = x + ((size_t)(n0 >> 12) << 20) + (n0 & 4095) + r;
        #pragma unroll 4
        for (int i = 0; i < 32; i += 2) {
            int c = cs * 32 + i;
            float g0 = xb[(size_t)c << 12];
            float g1 = xb[(size_t)(c + 1) << 12];
            u16 h0 = f2bf(g0), h1 = f2bf(g1);
            u16 e0 = f2bf(g0 - bf2f(h0)), e1 = f2bf(g1 - bf2f(h1));
            int byte = (r * 512 + c * 2) ^ ((r & 7) << 4);
            *(u32*)((char*)xh + byte) = (u32)h0 | ((u32)h1 << 16);
            *(u32*)((char*)xl + byte) = (u32)e0 | ((u32)e1 << 16);
        }
        b2_s[t] = b2g[t];  b2_s[512 + t] = b2g[512 + t];
        dn_s[t] = dnp[t];  dn_s[512 + t] = dnp[512 + t];
    }
    __syncthreads();

    // ---- rep zero-fill early (R3/R6-proven position)
    float* rep0 = out + 2 + (size_t)NELEM;
    {
        float2* zb = (float2*)(rep0 + ((size_t)n0 << 10));
        #pragma unroll 8
        for (int i = 0; i < 64; ++i) zb[i * 512 + t] = make_float2(0.f, 0.f);
    }

    const int arow = lane & 31, hl = lane >> 5;
    const int swz = (arow & 7) << 4;

    float m0 = -INFINITY, s0 = 0.f, m1 = -INFINITY, s1 = 0.f;
    u32 hk0[TOPK], hk1[TOPK];
    #pragma unroll
    for (int j = 0; j < TOPK; ++j) { hk0[j] = 0xFFFFFFFFu; hk1[j] = 0xFFFFFFFFu; }

    // ---- barrier-free main loop: 4 chunks of 256 atoms, wave owns 32/chunk,
    //      computes both 32-row tiles (atom fragments fetched once per block)
    #pragma unroll 1
    for (int ck = 0; ck < 4; ++ck) {
        const size_t abase = (size_t)((ck << 8) + (wid << 5) + arow);
        const u16* Wp  = Wh + (abase << 8) + hl * 8;
        const u16* Dhp = Dh + (abase << 8) + hl * 8;
        const u16* Dlp = Dl + (abase << 8) + hl * 8;
        const int cb = (ck << 8) + (wid << 5) + (hl << 2);

        // ---- L phase
        f32x16 accL0 = ZERO16, accL1 = ZERO16;
        __builtin_amdgcn_s_setprio(1);
        #pragma unroll 4
        for (int kst = 0; kst < 16; ++kst) {
            int bo = (arow * 512 + hl * 16 + kst * 32) ^ swz;
            s16x8 aw  = *(const s16x8*)(Wp + kst * 16);
            s16x8 bh0 = *(const s16x8*)((const char*)xh + bo);
            s16x8 bh1 = *(const s16x8*)((const char*)xh + bo + 32 * 512);
            accL0 = mfma16(aw, bh0, accL0);
            accL1 = mfma16(aw, bh1, accL1);
        }
        __builtin_amdgcn_s_setprio(0);

        float4 bv4[4];
        #pragma unroll
        for (int rg = 0; rg < 4; ++rg)
            bv4[rg] = *(const float4*)(b2_s + cb + rg * 8);
        SMAX_TILE(accL0, m0, s0)
        SMAX_TILE(accL1, m1, s1)

        // ---- D phase
        f32x16 accD0 = ZERO16, accD1 = ZERO16;
        __builtin_amdgcn_s_setprio(1);
        #pragma unroll 2
        for (int kst = 0; kst < 16; ++kst) {
            int bo = (arow * 512 + hl * 16 + kst * 32) ^ swz;
            s16x8 adh = *(const s16x8*)(Dhp + kst * 16);
            s16x8 adl = *(const s16x8*)(Dlp + kst * 16);
            s16x8 bh0 = *(const s16x8*)((const char*)xh + bo);
            s16x8 bl0 = *(const s16x8*)((const char*)xl + bo);
            s16x8 bh1 = *(const s16x8*)((const char*)xh + bo + 32 * 512);
            s16x8 bl1 = *(const s16x8*)((const char*)xl + bo + 32 * 512);
            accD0 = mfma16(adh, bh0, accD0);
            accD0 = mfma16(adh, bl0, accD0);
            accD0 = mfma16(adl, bh0, accD0);
            accD1 = mfma16(adh, bh1, accD1);
            accD1 = mfma16(adh, bl1, accD1);
            accD1 = mfma16(adl, bh1, accD1);
        }
        __builtin_amdgcn_s_setprio(0);

        float4 n44[4];
        #pragma unroll
        for (int rg = 0; rg < 4; ++rg)
            n44[rg] = *(const float4*)(dn_s + cb + rg * 8);
        const u32 ob = (u32)(ck << 4);
        #pragma unroll
        for (int rg = 0; rg < 4; ++rg) {
            u32 o0 = ob + rg * 4;
            float d0 = n44[rg].x + accD0[4*rg+0];
            float d1 = n44[rg].y + accD0[4*rg+1];
            float d2 = n44[rg].z + accD0[4*rg+2];
            float d3 = n44[rg].w + accD0[4*rg+3];
            INSP(hk0, (mono(d0) & ~63u) | (o0 + 0))
            INSP(hk0, (mono(d1) & ~63u) | (o0 + 1))
            INSP(hk0, (mono(d2) & ~63u) | (o0 + 2))
            INSP(hk0, (mono(d3) & ~63u) | (o0 + 3))
            float e0 = n44[rg].x + accD1[4*rg+0];
            float e1 = n44[rg].y + accD1[4*rg+1];
            float e2 = n44[rg].z + accD1[4*rg+2];
            float e3 = n44[rg].w + accD1[4*rg+3];
            INSP(hk1, (mono(e0) & ~63u) | (o0 + 0))
            INSP(hk1, (mono(e1) & ~63u) | (o0 + 1))
            INSP(hk1, (mono(e2) & ~63u) | (o0 + 2))
            INSP(hk1, (mono(e3) & ~63u) | (o0 + 3))
        }
    }

    // ---- decode packed keys -> (dist, global atom idx), lane-locally
    float hd0[TOPK], hd1[TOPK];
    int hix0[TOPK], hix1[TOPK];
    #pragma unroll
    for (int j = 0; j < TOPK; ++j) {
        u32 v = hk0[j]; int o = (int)(v & 63u);
        hd0[j] = unmono(v & ~63u);
        hix0[j] = ((o >> 4) << 8) + (wid << 5) + (((o >> 2) & 3) << 3) + (hl << 2) + (o & 3);
        v = hk1[j]; o = (int)(v & 63u);
        hd1[j] = unmono(v & ~63u);
        hix1[j] = ((o >> 4) << 8) + (wid << 5) + (((o >> 2) & 3) << 3) + (hl << 2) + (o & 3);
    }

    // ---- intra-wave merge (lane n <-> n+32: same rows, disjoint atoms)
    {
        float mo = __shfl_xor(m0, 32), so = __shfl_xor(s0, 32);
        float mn = fmaxf(m0, mo);
        s0 = s0 * exp2f(m0 - mn) + so * exp2f(mo - mn);
        m0 = mn;
        mo = __shfl_xor(m1, 32); so = __shfl_xor(s1, 32);
        mn = fmaxf(m1, mo);
        s1 = s1 * exp2f(m1 - mn) + so * exp2f(mo - mn);
        m1 = mn;
        float od[TOPK]; int oi[TOPK];
        #pragma unroll
        for (int j = 0; j < TOPK; ++j) {
            od[j] = __shfl_xor(hd0[j], 32); oi[j] = __shfl_xor(hix0[j], 32);
        }
        MERGE8(hd0, hix0, od, oi)
        #pragma unroll
        for (int j = 0; j < TOPK; ++j) {
            od[j] = __shfl_xor(hd1[j], 32); oi[j] = __shfl_xor(hix1[j], 32);
        }
        MERGE8(hd1, hix1, od, oi)
    }

    // ---- publish all 8 wave-lists per row (overlay on dead xl/b2)
    __syncthreads();
    {
        const int row = (lane < 32) ? arow : (arow + 32);
        const int base = row * 64 + wid * 8;
        if (lane < 32) {
            #pragma unroll
            for (int j = 0; j < TOPK; ++j) { pd[base + j] = hd0[j]; pi[base + j] = hix0[j]; }
            pm[row * 8 + wid] = m0; ps[row * 8 + wid] = s0;
        } else {
            #pragma unroll
            for (int j = 0; j < TOPK; ++j) { pd[base + j] = hd1[j]; pi[base + j] = hix1[j]; }
            pm[row * 8 + wid] = m1; ps[row * 8 + wid] = s1;
        }
    }
    __syncthreads();

    // ---- final merge: one 8-thread group per row, 3-round bitonic
    {
        const int row = t >> 3, src = t & 7;
        float hd[TOPK]; int hix[TOPK];
        #pragma unroll
        for (int j = 0; j < TOPK; ++j) {
            hd[j] = pd[row * 64 + src * 8 + j];
            hix[j] = pi[row * 64 + src * 8 + j];
        }
        float m = pm[row * 8 + src], s = ps[row * 8 + src];
        #pragma unroll
        for (int k = 1; k <= 4; k <<= 1) {
            float mo = __shfl_xor(m, k), so = __shfl_xor(s, k);
            float mn = fmaxf(m, mo);
            s = s * exp2f(m - mn) + so * exp2f(mo - mn);
            m = mn;
            float od[TOPK]; int oi[TOPK];
            #pragma unroll
            for (int j = 0; j < TOPK; ++j) {
                od[j] = __shfl_xor(hd[j], k); oi[j] = __shfl_xor(hix[j], k);
            }
            MERGE8(hd, hix, od, oi)
        }
        if (src == 0) {
            selm[row] = m;
            sels[row] = 1.0f / s;
            #pragma unroll
            for (int j = 0; j < TOPK; ++j) {
                seli[row * 8 + j] = hix[j];
                atomicAdd(&counts[hix[j]], 1);
            }
        }
    }
    __syncthreads();

    // ---- recompute winner logits from LDS xh (true x_flat rows) + fp32 W, b
    {
        const int row = t >> 3, j = t & 7;
        const int idxw = seli[row * 8 + j];
        const float4* wp = (const float4*)(Wm + ((size_t)idxw << 8));
        const int swr = (row & 7) << 4;
        float ax = 0.f, ay = 0.f, az = 0.f, aw2 = 0.f;
        #pragma unroll 8
        for (int i = 0; i < 32; ++i) {
            int byte = (row * 512 + i * 16) ^ swr;
            uint4 H = *(const uint4*)((const char*)xh + byte);
            float4 w0 = wp[i * 2], w1 = wp[i * 2 + 1];
            ax += bf2f((u16)H.x) * w0.x; ay += hi2f(H.x) * w0.y;
            az += bf2f((u16)H.y) * w0.z; aw2 += hi2f(H.y) * w0.w;
            ax += bf2f((u16)H.z) * w1.x; ay += hi2f(H.z) * w1.y;
            az += bf2f((u16)H.w) * w1.z; aw2 += hi2f(H.w) * w1.w;
        }
        float lg = (ax + ay) + (az + aw2) + bv[idxw];
        float p = exp2f(lg * L2E - selm[row]) * sels[row];
        selp[row * 8 + j] = p;
        float v2 = p;
        #pragma unroll
        for (int off = 32; off; off >>= 1) v2 += __shfl_down(v2, off);
        if (lane == 0) atomicAdd(reg_acc, v2);
    }
    __syncthreads();

    // ---- rep scatter
    {
        int rr = t >> 3, j = t & 7;
        rep0[((size_t)(n0 + rr) << 10) + seli[rr * 8 + j]] = selp[rr * 8 + j];
    }

    // ---- recon (flat .view semantics) + fused MSE vs x (flat, coalesced)
    float lsum = 0.f;
    {
        int rr = t >> 3, tl = t & 7;
        size_t n = (size_t)(n0 + rr);
        float acc[32];
        #pragma unroll
        for (int i = 0; i < 32; ++i) acc[i] = 0.f;
        #pragma unroll
        for (int j = 0; j < TOPK; ++j) {
            float p = selp[rr * 8 + j];
            const float* dp = dict + ((size_t)seli[rr * 8 + j] << 8) + tl * 32;
            #pragma unroll
            for (int i = 0; i < 32; i += 4) {
                float4 d4 = *(const float4*)(dp + i);
                acc[i]     += p * d4.x; acc[i + 1] += p * d4.y;
                acc[i + 2] += p * d4.z; acc[i + 3] += p * d4.w;
            }
        }
        const float* xf = x + (n << 8) + tl * 32;
        float* ro = out + 1 + (n << 8) + tl * 32;
        #pragma unroll
        for (int i = 0; i < 32; i += 4) {
            float4 xv = *(const float4*)(xf + i);
            float e0 = xv.x - acc[i],     e1 = xv.y - acc[i + 1];
            float e2 = xv.z - acc[i + 2], e3 = xv.w - acc[i + 3];
            lsum += e0 * e0 + e1 * e1 + e2 * e2 + e3 * e3;
            ro[i] = acc[i]; ro[i + 1] = acc[i + 1];
            ro[i + 2] = acc[i + 2]; ro[i + 3] = acc[i + 3];
        }
    }
    {
        #pragma unroll
        for (int off = 32; off; off >>= 1) lsum += __shfl_down(lsum, off);
        if (lane == 0) atomicAdd(loss_acc, lsum);
    }
}

// ---------------- finalize scalars -------------------------------------------
__global__ void dl_final(const float* __restrict__ loss_acc,
                         const float* __restrict__ reg_acc,
                         const int* __restrict__ counts,
                         float* __restrict__ out)
{
    __shared__ float red[4];
    int t = threadIdx.x;
    float e = 0.f;
    for (int k = t; k < KDIM; k += 256) {
        float p = (float)counts[k] * (1.0f / 524288.0f);
        e += p * logf(p + 1e-10f);
    }
    #pragma unroll
    for (int off = 32; off; off >>= 1) e += __shfl_down(e, off);
    if ((t & 63) == 0) red[t >> 6] = e;
    __syncthreads();
    if (t == 0) {
        float et = red[0] + red[1] + red[2] + red[3];
        out[(size_t)NELEM + 1] = __expf(-et);                     // perplexity
        out[0] = 2.0f * loss_acc[0] / (float)NELEM + reg_acc[0];  // loss + reg
    }
}

extern "C" void kernel_launch(void* const* d_in, const int* in_sizes, int n_in,
                              void* d_out, int out_size, void* d_ws, size_t ws_size,
                              hipStream_t stream) {
    const float* x    = (const float*)d_in[0];
    const float* dict = (const float*)d_in[1];
    const float* Wm   = (const float*)d_in[2];
    const float* bv   = (const float*)d_in[3];
    float* out = (float*)d_out;

    float* loss_acc = (float*)d_ws;
    float* reg_acc  = loss_acc + 1;
    int*   counts   = (int*)((char*)d_ws + WS_COUNTS);
    float* dn       = (float*)((char*)d_ws + WS_DN);
    float* b2       = (float*)((char*)d_ws + WS_B2);
    u16*   Wh       = (u16*)((char*)d_ws + WS_WH);
    u16*   Dh       = (u16*)((char*)d_ws + WS_DH);
    u16*   Dl       = (u16*)((char*)d_ws + WS_DL);

    hipMemsetAsync(d_ws, 0, 4608, stream);
    dl_prep<<<KDIM, 256, 0, stream>>>(Wm, dict, bv, Wh, Dh, Dl, dn, b2);
    dl_main<<<65536 / MROWS, 512, 0, stream>>>(x, dict, Wm, bv, Wh, Dh, Dl, dn,
                                               b2, out, loss_acc, reg_acc, counts);
    dl_final<<<1, 256, 0, stream>>>(loss_acc, reg_acc, counts, out);
}